// Round 6
// baseline (299.483 us; speedup 1.0000x reference)
//
#include <hip/hip_runtime.h>

typedef unsigned short u16;
typedef unsigned int u32;
typedef __attribute__((ext_vector_type(8))) short s16x8;
typedef __attribute__((ext_vector_type(4))) float f32x4;

#define MFMA(a,b,c) __builtin_amdgcn_mfma_f32_16x16x32_bf16((a),(b),(c),0,0,0)
#define QSCALE 0.18033688011112042f   // 0.125 * log2(e): folds attn scale + exp->exp2

__device__ __forceinline__ u16 bfc(float f){
  union { float f; unsigned int u; } c; c.f = f;
  return (u16)((c.u + 0x7fffu + ((c.u >> 16) & 1u)) >> 16);
}
// pack 2 f32 -> 2 bf16 (round-half-up) in one v_perm_b32
__device__ __forceinline__ u32 pkbf(float lo, float hi){
  union { float f; u32 u; } a, b; a.f = lo; b.f = hi;
  return __builtin_amdgcn_perm(b.u + 0x8000u, a.u + 0x8000u, 0x07060302u);
}
__device__ __forceinline__ float fexp2(float x){ return __builtin_amdgcn_exp2f(x); }
__device__ __forceinline__ f32x4 zero4(){ f32x4 z; z[0]=0.f; z[1]=0.f; z[2]=0.f; z[3]=0.f; return z; }

__device__ __forceinline__ void gload_lds16(const u16* g, u16* l){
  __builtin_amdgcn_global_load_lds((const __attribute__((address_space(1))) unsigned int*)g,
                                   (__attribute__((address_space(3))) unsigned int*)l, 16, 0, 0);
}

// ---------------- x fp32 -> bf16
__global__ __launch_bounds__(256) void k_cvt(const float* __restrict__ x, u16* __restrict__ xb){
  int i = (blockIdx.x * 256 + threadIdx.x) * 4;
  float4 v = *(const float4*)(x + i);
  *(uint2*)(xb + i) = make_uint2(pkbf(v.x, v.y), pkbf(v.z, v.w));
}

// ---------------- fused weight transpose+convert (Wq|Wk|Wv|Wo): [m][1024][64] f32 -> [m][64][1024] bf16
__global__ __launch_bounds__(256) void k_twp(const float* __restrict__ Wq, const float* __restrict__ Wk,
    const float* __restrict__ Wv, const float* __restrict__ Wo,
    u16* __restrict__ wt, u16* __restrict__ wot){
  __shared__ float t[64][65];
  int y = blockIdx.y, k0 = blockIdx.x * 64, tid = threadIdx.x;
  const float* src; u16* dst;
  if (y < 16)      { src = Wq + (size_t)y * 65536;        dst = wt + (size_t)y * 65536; }
  else if (y < 32) { src = Wk + (size_t)(y-16) * 65536;   dst = wt + (size_t)y * 65536; }
  else if (y < 48) { src = Wv + (size_t)(y-32) * 65536;   dst = wt + (size_t)y * 65536; }
  else             { src = Wo;                            dst = wot; }
  const float* s = src + (size_t)k0 * 64;
  int kl = tid >> 2, nc = (tid & 3) * 16;
  #pragma unroll
  for (int j = 0; j < 4; j++){
    float4 v = *(const float4*)(s + kl * 64 + nc + j * 4);
    t[kl][nc + j*4 + 0] = v.x; t[kl][nc + j*4 + 1] = v.y;
    t[kl][nc + j*4 + 2] = v.z; t[kl][nc + j*4 + 3] = v.w;
  }
  __syncthreads();
  int n = tid >> 2, kc = (tid & 3) * 16;
  u16 o[16];
  #pragma unroll
  for (int j = 0; j < 16; j++) o[j] = bfc(t[kc + j][n]);
  u16* d = dst + (size_t)n * 1024 + k0 + kc;
  *(uint4*)(d)     = *(uint4*)&o[0];
  *(uint4*)(d + 8) = *(uint4*)&o[8];
}

// ---------------- fused QKV projection: GEMM M=8192, N=3072, K=1024; 128x128 tile.
// XOR-swizzled LDS (R5): logical k-chunk lc at physical lc^(row&7) -> 2-way alias only.
__global__ __launch_bounds__(256) void k_qkv(const u16* __restrict__ xb, const u16* __restrict__ wt,
    const float* __restrict__ bq, const float* __restrict__ bk, const float* __restrict__ bv,
    u16* __restrict__ Qo, u16* __restrict__ Ko, u16* __restrict__ VT){
  __shared__ u16 As[128][64];
  __shared__ u16 Bs[128][64];
  int tid = threadIdx.x, wave = tid >> 6, lane = tid & 63;
  int l16 = lane & 15, g = lane >> 4;
  int row0 = blockIdx.x * 128, col0 = blockIdx.y * 128;
  int wm = (wave & 1) * 64, wn = (wave >> 1) * 64;
  f32x4 acc[4][4];
  #pragma unroll
  for (int mt = 0; mt < 4; mt++)
    #pragma unroll
    for (int nt = 0; nt < 4; nt++) acc[mt][nt] = zero4();
  int srow = (lane >> 3);
  int scol = ((lane & 7) ^ srow) * 8;             // swizzled logical chunk for this lane's slot
  for (int k0 = 0; k0 < 1024; k0 += 64){
    __syncthreads();
    #pragma unroll
    for (int p = 0; p < 4; p++){
      int r = wave * 32 + p * 8 + srow;
      gload_lds16(xb + (size_t)(row0 + r) * 1024 + k0 + scol, &As[wave * 32 + p * 8][0]);
      gload_lds16(wt + (size_t)(col0 + r) * 1024 + k0 + scol, &Bs[wave * 32 + p * 8][0]);
    }
    __syncthreads();
    #pragma unroll
    for (int c = 0; c < 2; c++){
      s16x8 af[4], bf[4];
      #pragma unroll
      for (int mt = 0; mt < 4; mt++)
        af[mt] = *(const s16x8*)&As[wm + mt*16 + l16][((c*4 + g) ^ (l16 & 7)) * 8];
      #pragma unroll
      for (int nt = 0; nt < 4; nt++)
        bf[nt] = *(const s16x8*)&Bs[wn + nt*16 + l16][((c*4 + g) ^ (l16 & 7)) * 8];
      #pragma unroll
      for (int mt = 0; mt < 4; mt++)
        #pragma unroll
        for (int nt = 0; nt < 4; nt++) acc[mt][nt] = MFMA(af[mt], bf[nt], acc[mt][nt]);
    }
  }
  #pragma unroll
  for (int nt = 0; nt < 4; nt++){
    int n = col0 + wn + nt * 16 + l16;
    int wi = n >> 10, hh = (n >> 6) & 15, dh = n & 63;
    const float* bptr = (wi == 0) ? bq : (wi == 1) ? bk : bv;
    float bval = bptr[hh * 64 + dh];
    #pragma unroll
    for (int mt = 0; mt < 4; mt++){
      int m0 = row0 + wm + mt * 16 + g * 4;
      int bb = m0 >> 11, ss = m0 & 2047;
      if (wi == 2){
        u32 p0 = pkbf(acc[mt][nt][0] + bval, acc[mt][nt][1] + bval);
        u32 p1 = pkbf(acc[mt][nt][2] + bval, acc[mt][nt][3] + bval);
        *(uint2*)&VT[(((size_t)bb * 16 + hh) * 64 + dh) * 2048 + ss] = make_uint2(p0, p1);
      } else {
        u16* dst = (wi == 0) ? Qo : Ko;
        float scl = (wi == 0) ? QSCALE : 1.0f;
        #pragma unroll
        for (int i = 0; i < 4; i++)
          dst[(((size_t)bb * 16 + hh) * 2048 + ss + i) * 64 + dh] = bfc((acc[mt][nt][i] + bval) * scl);
      }
    }
  }
}

// ---------------- flash attention v3: S^T + fixed-max softmax + DIRECT global->register
// K/V fragment loads (A-layout: 16B/lane) -- no K/V LDS staging, NO barriers in k-loop.
// Block = 512 thr = 8 waves = 4 qg (32 q each) x 2 kg (32 k-slice). Triangle-paired.
// LDS: per-wave Ps round-trip only; merge overlay reused after k-loop.
__global__ __launch_bounds__(512, 4) void k_attn(const u16* __restrict__ Q, const u16* __restrict__ Kg,
    const u16* __restrict__ VT, u16* __restrict__ O){
  __shared__ u16 smem[17408];           // 34816B: Ps 8 waves x [2][16][36] = 18432B; merge 32KB+2KB
  float* mg = (float*)smem;             // [qg*8 + mt*2 + j][64 lane][4] f32 = 32KB
  float* lg = (float*)smem + 8192;      // [qg*64 + lane][2] f32 = 2KB
  int hbi = blockIdx.x, pair = blockIdx.y;
  int b = hbi >> 4, h = hbi & 15;
  int tid = threadIdx.x, wave = tid >> 6, lane = tid & 63;
  int l16 = lane & 15, g = lane >> 4;
  int qg = wave >> 1, kg = wave & 1;
  size_t hb = (size_t)hbi * 2048 * 64;
  const u16* kbase = Kg + hb;
  const u16* vbase = VT + hb;           // [64][2048]
  u16* PsW = smem + wave * 1152;        // [2 j][16 q][36]
  // per-wave V^T row pointers (dh rows fixed across iters)
  const u16* vrow[4];
  #pragma unroll
  for (int mt = 0; mt < 4; mt++) vrow[mt] = vbase + (size_t)(mt*16 + l16) * 2048 + g*8;
  #pragma unroll
  for (int ph = 0; ph < 2; ph++){
    int qt = ph ? pair : (15 - pair);
    int qbase = qt * 128;
    int q0 = qbase + qg * 32;           // wave's 32 q-rows
    s16x8 bq[2][2];
    #pragma unroll
    for (int j = 0; j < 2; j++)
      #pragma unroll
      for (int c = 0; c < 2; c++)
        bq[j][c] = *(const s16x8*)(Q + hb + (size_t)(q0 + j*16 + l16) * 64 + c*32 + g*8);
    f32x4 accO[4][2];                   // [mt(dh)][j(q)]
    #pragma unroll
    for (int mt = 0; mt < 4; mt++){ accO[mt][0] = zero4(); accO[mt][1] = zero4(); }
    float rsacc[2] = {0.f, 0.f};        // per-lane partial row sums
    int nkt = 2 * qt + 2;
    __syncthreads();                    // prev phase merge-readers done before Ps reuse
    for (int kt = 0; kt < nkt; kt++){
      int ks0 = kt * 64 + kg * 32;      // wave's absolute k-slice start
      if (ks0 > q0 + 31) continue;      // wave-uniform; no barriers in loop
      // direct A-fragment loads: K (m=kpos,k=dh), V^T (m=dh,k=kpos)
      s16x8 ak[2][2], av[4];
      #pragma unroll
      for (int t = 0; t < 2; t++)
        #pragma unroll
        for (int c = 0; c < 2; c++)
          ak[t][c] = *(const s16x8*)(kbase + (size_t)(ks0 + t*16 + l16) * 64 + c*32 + g*8);
      #pragma unroll
      for (int mt = 0; mt < 4; mt++)
        av[mt] = *(const s16x8*)(vrow[mt] + ks0);
      #pragma unroll
      for (int j = 0; j < 2; j++){
        f32x4 s0 = zero4(), s1 = zero4();
        s0 = MFMA(ak[0][0], bq[j][0], s0);
        s0 = MFMA(ak[0][1], bq[j][1], s0);
        s1 = MFMA(ak[1][0], bq[j][0], s1);
        s1 = MFMA(ak[1][1], bq[j][1], s1);
        if (ks0 + 31 > q0 + j*16){      // diagonal straddle: causal mask
          int qrow = q0 + j*16 + l16;
          #pragma unroll
          for (int r = 0; r < 4; r++){
            if (ks0 + g*4 + r      > qrow) s0[r] = -1e30f;
            if (ks0 + 16 + g*4 + r > qrow) s1[r] = -1e30f;
          }
        }
        float p00 = fexp2(s0[0]), p01 = fexp2(s0[1]), p02 = fexp2(s0[2]), p03 = fexp2(s0[3]);
        float p10 = fexp2(s1[0]), p11 = fexp2(s1[1]), p12 = fexp2(s1[2]), p13 = fexp2(s1[3]);
        rsacc[j] += ((p00 + p01) + (p02 + p03)) + ((p10 + p11) + (p12 + p13));
        u16* pr = PsW + (j*16 + l16) * 36;
        *(uint2*)&pr[g*4]      = make_uint2(pkbf(p00, p01), pkbf(p02, p03));
        *(uint2*)&pr[16 + g*4] = make_uint2(pkbf(p10, p11), pkbf(p12, p13));
      }
      #pragma unroll
      for (int j = 0; j < 2; j++){      // O^T += V^T(slice) * P^T
        s16x8 bp = *(const s16x8*)&PsW[(j*16 + l16) * 36 + g*8];
        #pragma unroll
        for (int mt = 0; mt < 4; mt++)
          accO[mt][j] = MFMA(av[mt], bp, accO[mt][j]);
      }
    }
    // cross-wave (kg) merge of accO and l, then kg=0 normalizes + stores
    __syncthreads();
    if (kg == 1){
      #pragma unroll
      for (int mt = 0; mt < 4; mt++)
        #pragma unroll
        for (int j = 0; j < 2; j++)
          *(f32x4*)&mg[((qg*8 + mt*2 + j) * 64 + lane) * 4] = accO[mt][j];
      lg[(qg*64 + lane)*2 + 0] = rsacc[0];
      lg[(qg*64 + lane)*2 + 1] = rsacc[1];
    }
    __syncthreads();
    if (kg == 0){
      float rinv[2];
      #pragma unroll
      for (int j = 0; j < 2; j++){
        float l = rsacc[j] + lg[(qg*64 + lane)*2 + j];
        l += __shfl_xor(l, 16);
        l += __shfl_xor(l, 32);
        rinv[j] = 1.0f / l;
      }
      #pragma unroll
      for (int mt = 0; mt < 4; mt++)
        #pragma unroll
        for (int j = 0; j < 2; j++){
          f32x4 part = *(f32x4*)&mg[((qg*8 + mt*2 + j) * 64 + lane) * 4];
          float o0 = (accO[mt][j][0] + part[0]) * rinv[j];
          float o1 = (accO[mt][j][1] + part[1]) * rinv[j];
          float o2 = (accO[mt][j][2] + part[2]) * rinv[j];
          float o3 = (accO[mt][j][3] + part[3]) * rinv[j];
          *(uint2*)&O[((size_t)b * 2048 + q0 + j*16 + l16) * 1024 + h*64 + mt*16 + g*4] =
              make_uint2(pkbf(o0, o1), pkbf(o2, o3));
        }
    }
  }
}

// ---------------- output projection with split-K=4: [8192,1024] @ Wo^T + bo -> fp32 (atomicAdd)
__global__ __launch_bounds__(256) void k_oproj(const u16* __restrict__ Ob, const u16* __restrict__ wot,
    const float* __restrict__ bo, float* __restrict__ out){
  __shared__ u16 As[64][72];
  __shared__ u16 Bs[64][72];
  int rb = blockIdx.x, kc = blockIdx.y;
  int tid = threadIdx.x, wave = tid >> 6, lane = tid & 63;
  int l16 = lane & 15, g = lane >> 4;
  int wr = (wave & 1) * 32, wc = (wave >> 1) * 32;
  int row0 = rb * 64;
  f32x4 acc[2][2];
  acc[0][0]=zero4(); acc[0][1]=zero4(); acc[1][0]=zero4(); acc[1][1]=zero4();
  int r0s = tid >> 3, cc0 = (tid & 7) * 8, r1s = r0s + 32;
  for (int k0 = kc * 256; k0 < kc * 256 + 256; k0 += 64){
    __syncthreads();
    *(uint4*)&As[r0s][cc0] = *(const uint4*)(Ob + (size_t)(row0 + r0s) * 1024 + k0 + cc0);
    *(uint4*)&As[r1s][cc0] = *(const uint4*)(Ob + (size_t)(row0 + r1s) * 1024 + k0 + cc0);
    *(uint4*)&Bs[r0s][cc0] = *(const uint4*)(wot + (size_t)r0s * 1024 + k0 + cc0);
    *(uint4*)&Bs[r1s][cc0] = *(const uint4*)(wot + (size_t)r1s * 1024 + k0 + cc0);
    __syncthreads();
    #pragma unroll
    for (int c = 0; c < 2; c++){
      int kcc = c * 32;
      s16x8 a0 = *(const s16x8*)&As[wr      + l16][kcc + g * 8];
      s16x8 a1 = *(const s16x8*)&As[wr + 16 + l16][kcc + g * 8];
      s16x8 b0 = *(const s16x8*)&Bs[wc      + l16][kcc + g * 8];
      s16x8 b1 = *(const s16x8*)&Bs[wc + 16 + l16][kcc + g * 8];
      acc[0][0] = MFMA(a0, b0, acc[0][0]);
      acc[0][1] = MFMA(a0, b1, acc[0][1]);
      acc[1][0] = MFMA(a1, b0, acc[1][0]);
      acc[1][1] = MFMA(a1, b1, acc[1][1]);
    }
  }
  #pragma unroll
  for (int rt = 0; rt < 2; rt++){
    #pragma unroll
    for (int ct = 0; ct < 2; ct++){
      int col = wc + ct * 16 + l16;
      float bval = (kc == 0) ? bo[col] : 0.f;
      #pragma unroll
      for (int i = 0; i < 4; i++){
        int row = row0 + wr + rt * 16 + g * 4 + i;
        atomicAdd(&out[(size_t)row * 64 + col], acc[rt][ct][i] + bval);
      }
    }
  }
}

extern "C" void kernel_launch(void* const* d_in, const int* in_sizes, int n_in,
                              void* d_out, int out_size, void* d_ws, size_t ws_size,
                              hipStream_t stream){
  const float* x  = (const float*)d_in[0];
  const float* Wq = (const float*)d_in[1];
  const float* bq = (const float*)d_in[2];
  const float* Wk = (const float*)d_in[3];
  const float* bk = (const float*)d_in[4];
  const float* Wv = (const float*)d_in[5];
  const float* bv = (const float*)d_in[6];
  const float* Wo = (const float*)d_in[7];
  const float* bo = (const float*)d_in[8];

  u16* xb  = (u16*)d_ws;          // [8192][1024] bf16 x ; reused as attention output Ob
  u16* wt  = xb  + 8388608;       // [3][16][64][1024] transposed qkv weights
  u16* wot = wt  + 3145728;       // [64][1024] transposed Wo
  u16* Qb  = wot + 65536;         // [B][H][S][64] (pre-scaled by QSCALE)
  u16* Kb  = Qb  + 8388608;       // [B][H][S][64]
  u16* VTb = Kb  + 8388608;       // [B][H][64][S]
  u16* Ob  = xb;                  // alias: x dead after k_qkv
  float* out = (float*)d_out;

  hipMemsetAsync(d_out, 0, (size_t)out_size * sizeof(float), stream);
  k_cvt<<<8192, 256, 0, stream>>>(x, xb);
  k_twp<<<dim3(16, 49), 256, 0, stream>>>(Wq, Wk, Wv, Wo, wt, wot);
  k_qkv<<<dim3(64, 24), 256, 0, stream>>>(xb, wt, bq, bk, bv, Qb, Kb, VTb);
  k_attn<<<dim3(64, 8), 512, 0, stream>>>(Qb, Kb, VTb, Ob);
  k_oproj<<<dim3(128, 4), 256, 0, stream>>>(Ob, wot, bo, out);
}

// Round 7
// 259.331 us; speedup vs baseline: 1.1548x; 1.1548x over previous
//
#include <hip/hip_runtime.h>

typedef unsigned short u16;
typedef unsigned int u32;
typedef __attribute__((ext_vector_type(8))) short s16x8;
typedef __attribute__((ext_vector_type(4))) float f32x4;

#define MFMA(a,b,c) __builtin_amdgcn_mfma_f32_16x16x32_bf16((a),(b),(c),0,0,0)
#define QSCALE 0.18033688011112042f   // 0.125 * log2(e): folds attn scale + exp->exp2

__device__ __forceinline__ u16 bfc(float f){
  union { float f; unsigned int u; } c; c.f = f;
  return (u16)((c.u + 0x7fffu + ((c.u >> 16) & 1u)) >> 16);
}
// pack 2 f32 -> 2 bf16 (round-half-up) in one v_perm_b32
__device__ __forceinline__ u32 pkbf(float lo, float hi){
  union { float f; u32 u; } a, b; a.f = lo; b.f = hi;
  return __builtin_amdgcn_perm(b.u + 0x8000u, a.u + 0x8000u, 0x07060302u);
}
__device__ __forceinline__ float fexp2(float x){ return __builtin_amdgcn_exp2f(x); }
__device__ __forceinline__ f32x4 zero4(){ f32x4 z; z[0]=0.f; z[1]=0.f; z[2]=0.f; z[3]=0.f; return z; }

__device__ __forceinline__ void gload_lds16(const u16* g, u16* l){
  __builtin_amdgcn_global_load_lds((const __attribute__((address_space(1))) unsigned int*)g,
                                   (__attribute__((address_space(3))) unsigned int*)l, 16, 0, 0);
}

// ---------------- x fp32 -> bf16
__global__ __launch_bounds__(256) void k_cvt(const float* __restrict__ x, u16* __restrict__ xb){
  int i = (blockIdx.x * 256 + threadIdx.x) * 4;
  float4 v = *(const float4*)(x + i);
  *(uint2*)(xb + i) = make_uint2(pkbf(v.x, v.y), pkbf(v.z, v.w));
}

// ---------------- fused weight transpose+convert (Wq|Wk|Wv|Wo): [m][1024][64] f32 -> [m][64][1024] bf16
__global__ __launch_bounds__(256) void k_twp(const float* __restrict__ Wq, const float* __restrict__ Wk,
    const float* __restrict__ Wv, const float* __restrict__ Wo,
    u16* __restrict__ wt, u16* __restrict__ wot){
  __shared__ float t[64][65];
  int y = blockIdx.y, k0 = blockIdx.x * 64, tid = threadIdx.x;
  const float* src; u16* dst;
  if (y < 16)      { src = Wq + (size_t)y * 65536;        dst = wt + (size_t)y * 65536; }
  else if (y < 32) { src = Wk + (size_t)(y-16) * 65536;   dst = wt + (size_t)y * 65536; }
  else if (y < 48) { src = Wv + (size_t)(y-32) * 65536;   dst = wt + (size_t)y * 65536; }
  else             { src = Wo;                            dst = wot; }
  const float* s = src + (size_t)k0 * 64;
  int kl = tid >> 2, nc = (tid & 3) * 16;
  #pragma unroll
  for (int j = 0; j < 4; j++){
    float4 v = *(const float4*)(s + kl * 64 + nc + j * 4);
    t[kl][nc + j*4 + 0] = v.x; t[kl][nc + j*4 + 1] = v.y;
    t[kl][nc + j*4 + 2] = v.z; t[kl][nc + j*4 + 3] = v.w;
  }
  __syncthreads();
  int n = tid >> 2, kc = (tid & 3) * 16;
  u16 o[16];
  #pragma unroll
  for (int j = 0; j < 16; j++) o[j] = bfc(t[kc + j][n]);
  u16* d = dst + (size_t)n * 1024 + k0 + kc;
  *(uint4*)(d)     = *(uint4*)&o[0];
  *(uint4*)(d + 8) = *(uint4*)&o[8];
}

// ---------------- fused QKV projection: GEMM M=8192, N=3072, K=1024; 128x128 tile.
// XOR-swizzled LDS (R5): logical k-chunk lc at physical lc^(row&7) -> 2-way alias only.
__global__ __launch_bounds__(256) void k_qkv(const u16* __restrict__ xb, const u16* __restrict__ wt,
    const float* __restrict__ bq, const float* __restrict__ bk, const float* __restrict__ bv,
    u16* __restrict__ Qo, u16* __restrict__ Ko, u16* __restrict__ VT){
  __shared__ u16 As[128][64];
  __shared__ u16 Bs[128][64];
  int tid = threadIdx.x, wave = tid >> 6, lane = tid & 63;
  int l16 = lane & 15, g = lane >> 4;
  int row0 = blockIdx.x * 128, col0 = blockIdx.y * 128;
  int wm = (wave & 1) * 64, wn = (wave >> 1) * 64;
  f32x4 acc[4][4];
  #pragma unroll
  for (int mt = 0; mt < 4; mt++)
    #pragma unroll
    for (int nt = 0; nt < 4; nt++) acc[mt][nt] = zero4();
  int srow = (lane >> 3);
  int scol = ((lane & 7) ^ srow) * 8;             // swizzled logical chunk for this lane's slot
  for (int k0 = 0; k0 < 1024; k0 += 64){
    __syncthreads();
    #pragma unroll
    for (int p = 0; p < 4; p++){
      int r = wave * 32 + p * 8 + srow;
      gload_lds16(xb + (size_t)(row0 + r) * 1024 + k0 + scol, &As[wave * 32 + p * 8][0]);
      gload_lds16(wt + (size_t)(col0 + r) * 1024 + k0 + scol, &Bs[wave * 32 + p * 8][0]);
    }
    __syncthreads();
    #pragma unroll
    for (int c = 0; c < 2; c++){
      s16x8 af[4], bf[4];
      #pragma unroll
      for (int mt = 0; mt < 4; mt++)
        af[mt] = *(const s16x8*)&As[wm + mt*16 + l16][((c*4 + g) ^ (l16 & 7)) * 8];
      #pragma unroll
      for (int nt = 0; nt < 4; nt++)
        bf[nt] = *(const s16x8*)&Bs[wn + nt*16 + l16][((c*4 + g) ^ (l16 & 7)) * 8];
      #pragma unroll
      for (int mt = 0; mt < 4; mt++)
        #pragma unroll
        for (int nt = 0; nt < 4; nt++) acc[mt][nt] = MFMA(af[mt], bf[nt], acc[mt][nt]);
    }
  }
  #pragma unroll
  for (int nt = 0; nt < 4; nt++){
    int n = col0 + wn + nt * 16 + l16;
    int wi = n >> 10, hh = (n >> 6) & 15, dh = n & 63;
    const float* bptr = (wi == 0) ? bq : (wi == 1) ? bk : bv;
    float bval = bptr[hh * 64 + dh];
    #pragma unroll
    for (int mt = 0; mt < 4; mt++){
      int m0 = row0 + wm + mt * 16 + g * 4;
      int bb = m0 >> 11, ss = m0 & 2047;
      if (wi == 2){
        u32 p0 = pkbf(acc[mt][nt][0] + bval, acc[mt][nt][1] + bval);
        u32 p1 = pkbf(acc[mt][nt][2] + bval, acc[mt][nt][3] + bval);
        *(uint2*)&VT[(((size_t)bb * 16 + hh) * 64 + dh) * 2048 + ss] = make_uint2(p0, p1);
      } else {
        u16* dst = (wi == 0) ? Qo : Ko;
        float scl = (wi == 0) ? QSCALE : 1.0f;
        #pragma unroll
        for (int i = 0; i < 4; i++)
          dst[(((size_t)bb * 16 + hh) * 2048 + ss + i) * 64 + dh] = bfc((acc[mt][nt][i] + bval) * scl);
      }
    }
  }
}

// ---------------- flash attention v4: R5's LDS-staged structure at 512 threads.
// Block = 8 waves = 4 qg (32 q) x 2 kg (32 k-slice); 128 q-rows/block, triangle-paired.
// K/V staged to LDS each kt (1 uint4/thread/buffer, register-prefetched); fixed-max
// softmax; per-wave Ps round-trip; cross-kg merge via LDS overlay after the k-loop.
__global__ __launch_bounds__(512, 4) void k_attn(const u16* __restrict__ Q, const u16* __restrict__ Kg,
    const u16* __restrict__ VT, u16* __restrict__ O){
  __shared__ u16 smem[18432];           // 36864B: Ks[64][72] | Vt[64][72] | Ps 8x[2][16][36]
  u16* Ks = smem;                       // [kpos][dh], stride 72
  u16* Vt = smem + 4608;                // [dh][kpos], stride 72
  u16* Ps = smem + 9216;
  float* mg = (float*)smem;             // merge overlay: [qg*8+mt*2+j][64 lane][4] = 32KB
  float* lg = (float*)smem + 8192;      // [qg*64+lane][2] = 2KB (Ps area is dead at merge time)
  int hbi = blockIdx.x, pair = blockIdx.y;
  int b = hbi >> 4, h = hbi & 15;
  int tid = threadIdx.x, wave = tid >> 6, lane = tid & 63;
  int l16 = lane & 15, g = lane >> 4;
  int qg = wave >> 1, kg = wave & 1;
  size_t hb = (size_t)hbi * 2048 * 64;
  const u16* kbase = Kg + hb;
  const u16* vbase = VT + hb;           // [64][2048]
  int sr = tid >> 3, scc = (tid & 7) * 8;   // 512 thr cover 64x64 u16: one 16B chunk each
  u16* PsW = Ps + wave * 1152;          // [2 j][16 q][36]
  #pragma unroll
  for (int ph = 0; ph < 2; ph++){
    int qt = ph ? pair : (15 - pair);
    int qbase = qt * 128;
    int q0 = qbase + qg * 32;           // wave's 32 q-rows
    s16x8 bq[2][2];
    #pragma unroll
    for (int j = 0; j < 2; j++)
      #pragma unroll
      for (int c = 0; c < 2; c++)
        bq[j][c] = *(const s16x8*)(Q + hb + (size_t)(q0 + j*16 + l16) * 64 + c*32 + g*8);
    f32x4 accO[4][2];                   // [mt(dh)][j(q)]
    #pragma unroll
    for (int mt = 0; mt < 4; mt++){ accO[mt][0] = zero4(); accO[mt][1] = zero4(); }
    float rsacc[2] = {0.f, 0.f};
    int nkt = 2 * qt + 2;
    uint4 ka, va;
    __syncthreads();                    // prev phase merge-readers done before restage
    ka = *(const uint4*)(kbase + (size_t)sr * 64 + scc);
    va = *(const uint4*)(vbase + (size_t)sr * 2048 + scc);
    *(uint4*)&Ks[sr * 72 + scc] = ka;
    *(uint4*)&Vt[sr * 72 + scc] = va;
    __syncthreads();
    for (int kt = 0; kt < nkt; kt++){
      if (kt + 1 < nkt){                // register-prefetch next K/V tile
        int kb2 = (kt + 1) * 64;
        ka = *(const uint4*)(kbase + (size_t)(kb2 + sr) * 64 + scc);
        va = *(const uint4*)(vbase + (size_t)sr * 2048 + kb2 + scc);
      }
      int ks0 = kt * 64 + kg * 32;      // wave's absolute k-slice start
      if (ks0 <= q0 + 31){              // wave-uniform activity (barriers stay outside)
        s16x8 ak[2][2], av[4];
        #pragma unroll
        for (int t = 0; t < 2; t++)
          #pragma unroll
          for (int c = 0; c < 2; c++)
            ak[t][c] = *(const s16x8*)&Ks[(kg*32 + t*16 + l16) * 72 + c*32 + g*8];
        #pragma unroll
        for (int mt = 0; mt < 4; mt++)
          av[mt] = *(const s16x8*)&Vt[(mt*16 + l16) * 72 + kg*32 + g*8];
        #pragma unroll
        for (int j = 0; j < 2; j++){
          f32x4 s0 = zero4(), s1 = zero4();
          s0 = MFMA(ak[0][0], bq[j][0], s0);
          s0 = MFMA(ak[0][1], bq[j][1], s0);
          s1 = MFMA(ak[1][0], bq[j][0], s1);
          s1 = MFMA(ak[1][1], bq[j][1], s1);
          if (ks0 + 31 > q0 + j*16){    // diagonal straddle: causal mask
            int qrow = q0 + j*16 + l16;
            #pragma unroll
            for (int r = 0; r < 4; r++){
              if (ks0 + g*4 + r      > qrow) s0[r] = -1e30f;
              if (ks0 + 16 + g*4 + r > qrow) s1[r] = -1e30f;
            }
          }
          float p00 = fexp2(s0[0]), p01 = fexp2(s0[1]), p02 = fexp2(s0[2]), p03 = fexp2(s0[3]);
          float p10 = fexp2(s1[0]), p11 = fexp2(s1[1]), p12 = fexp2(s1[2]), p13 = fexp2(s1[3]);
          rsacc[j] += ((p00 + p01) + (p02 + p03)) + ((p10 + p11) + (p12 + p13));
          u16* pr = PsW + (j*16 + l16) * 36;
          *(uint2*)&pr[g*4]      = make_uint2(pkbf(p00, p01), pkbf(p02, p03));
          *(uint2*)&pr[16 + g*4] = make_uint2(pkbf(p10, p11), pkbf(p12, p13));
        }
        #pragma unroll
        for (int j = 0; j < 2; j++){    // O^T += V^T(slice) * P^T
          s16x8 bp = *(const s16x8*)&PsW[(j*16 + l16) * 36 + g*8];
          #pragma unroll
          for (int mt = 0; mt < 4; mt++)
            accO[mt][j] = MFMA(av[mt], bp, accO[mt][j]);
        }
      }
      if (kt + 1 < nkt){
        __syncthreads();
        *(uint4*)&Ks[sr * 72 + scc] = ka;
        *(uint4*)&Vt[sr * 72 + scc] = va;
        __syncthreads();
      }
    }
    // cross-wave (kg) merge of accO and l, then kg=0 normalizes + stores
    __syncthreads();
    if (kg == 1){
      #pragma unroll
      for (int mt = 0; mt < 4; mt++)
        #pragma unroll
        for (int j = 0; j < 2; j++)
          *(f32x4*)&mg[((qg*8 + mt*2 + j) * 64 + lane) * 4] = accO[mt][j];
      lg[(qg*64 + lane)*2 + 0] = rsacc[0];
      lg[(qg*64 + lane)*2 + 1] = rsacc[1];
    }
    __syncthreads();
    if (kg == 0){
      float rinv[2];
      #pragma unroll
      for (int j = 0; j < 2; j++){
        float l = rsacc[j] + lg[(qg*64 + lane)*2 + j];
        l += __shfl_xor(l, 16);
        l += __shfl_xor(l, 32);
        rinv[j] = 1.0f / l;
      }
      #pragma unroll
      for (int mt = 0; mt < 4; mt++)
        #pragma unroll
        for (int j = 0; j < 2; j++){
          f32x4 part = *(f32x4*)&mg[((qg*8 + mt*2 + j) * 64 + lane) * 4];
          float o0 = (accO[mt][j][0] + part[0]) * rinv[j];
          float o1 = (accO[mt][j][1] + part[1]) * rinv[j];
          float o2 = (accO[mt][j][2] + part[2]) * rinv[j];
          float o3 = (accO[mt][j][3] + part[3]) * rinv[j];
          *(uint2*)&O[((size_t)b * 2048 + q0 + j*16 + l16) * 1024 + h*64 + mt*16 + g*4] =
              make_uint2(pkbf(o0, o1), pkbf(o2, o3));
        }
    }
  }
}

// ---------------- output projection with split-K=4: [8192,1024] @ Wo^T + bo -> fp32 (atomicAdd)
__global__ __launch_bounds__(256) void k_oproj(const u16* __restrict__ Ob, const u16* __restrict__ wot,
    const float* __restrict__ bo, float* __restrict__ out){
  __shared__ u16 As[64][72];
  __shared__ u16 Bs[64][72];
  int rb = blockIdx.x, kc = blockIdx.y;
  int tid = threadIdx.x, wave = tid >> 6, lane = tid & 63;
  int l16 = lane & 15, g = lane >> 4;
  int wr = (wave & 1) * 32, wc = (wave >> 1) * 32;
  int row0 = rb * 64;
  f32x4 acc[2][2];
  acc[0][0]=zero4(); acc[0][1]=zero4(); acc[1][0]=zero4(); acc[1][1]=zero4();
  int r0s = tid >> 3, cc0 = (tid & 7) * 8, r1s = r0s + 32;
  for (int k0 = kc * 256; k0 < kc * 256 + 256; k0 += 64){
    __syncthreads();
    *(uint4*)&As[r0s][cc0] = *(const uint4*)(Ob + (size_t)(row0 + r0s) * 1024 + k0 + cc0);
    *(uint4*)&As[r1s][cc0] = *(const uint4*)(Ob + (size_t)(row0 + r1s) * 1024 + k0 + cc0);
    *(uint4*)&Bs[r0s][cc0] = *(const uint4*)(wot + (size_t)r0s * 1024 + k0 + cc0);
    *(uint4*)&Bs[r1s][cc0] = *(const uint4*)(wot + (size_t)r1s * 1024 + k0 + cc0);
    __syncthreads();
    #pragma unroll
    for (int c = 0; c < 2; c++){
      int kcc = c * 32;
      s16x8 a0 = *(const s16x8*)&As[wr      + l16][kcc + g * 8];
      s16x8 a1 = *(const s16x8*)&As[wr + 16 + l16][kcc + g * 8];
      s16x8 b0 = *(const s16x8*)&Bs[wc      + l16][kcc + g * 8];
      s16x8 b1 = *(const s16x8*)&Bs[wc + 16 + l16][kcc + g * 8];
      acc[0][0] = MFMA(a0, b0, acc[0][0]);
      acc[0][1] = MFMA(a0, b1, acc[0][1]);
      acc[1][0] = MFMA(a1, b0, acc[1][0]);
      acc[1][1] = MFMA(a1, b1, acc[1][1]);
    }
  }
  #pragma unroll
  for (int rt = 0; rt < 2; rt++){
    #pragma unroll
    for (int ct = 0; ct < 2; ct++){
      int col = wc + ct * 16 + l16;
      float bval = (kc == 0) ? bo[col] : 0.f;
      #pragma unroll
      for (int i = 0; i < 4; i++){
        int row = row0 + wr + rt * 16 + g * 4 + i;
        atomicAdd(&out[(size_t)row * 64 + col], acc[rt][ct][i] + bval);
      }
    }
  }
}

extern "C" void kernel_launch(void* const* d_in, const int* in_sizes, int n_in,
                              void* d_out, int out_size, void* d_ws, size_t ws_size,
                              hipStream_t stream){
  const float* x  = (const float*)d_in[0];
  const float* Wq = (const float*)d_in[1];
  const float* bq = (const float*)d_in[2];
  const float* Wk = (const float*)d_in[3];
  const float* bk = (const float*)d_in[4];
  const float* Wv = (const float*)d_in[5];
  const float* bv = (const float*)d_in[6];
  const float* Wo = (const float*)d_in[7];
  const float* bo = (const float*)d_in[8];

  u16* xb  = (u16*)d_ws;          // [8192][1024] bf16 x ; reused as attention output Ob
  u16* wt  = xb  + 8388608;       // [3][16][64][1024] transposed qkv weights
  u16* wot = wt  + 3145728;       // [64][1024] transposed Wo
  u16* Qb  = wot + 65536;         // [B][H][S][64] (pre-scaled by QSCALE)
  u16* Kb  = Qb  + 8388608;       // [B][H][S][64]
  u16* VTb = Kb  + 8388608;       // [B][H][64][S]
  u16* Ob  = xb;                  // alias: x dead after k_qkv
  float* out = (float*)d_out;

  hipMemsetAsync(d_out, 0, (size_t)out_size * sizeof(float), stream);
  k_cvt<<<8192, 256, 0, stream>>>(x, xb);
  k_twp<<<dim3(16, 49), 256, 0, stream>>>(Wq, Wk, Wv, Wo, wt, wot);
  k_qkv<<<dim3(64, 24), 256, 0, stream>>>(xb, wt, bq, bk, bv, Qb, Kb, VTb);
  k_attn<<<dim3(64, 8), 512, 0, stream>>>(Qb, Kb, VTb, Ob);
  k_oproj<<<dim3(128, 4), 256, 0, stream>>>(Ob, wot, bo, out);
}